// Round 1
// baseline (473.760 us; speedup 1.0000x reference)
//
#include <hip/hip_runtime.h>
#include <math.h>

#define CC  256
#define SP  8                 // floats per LDS element slot (32B = 2x float4)
#define NY  (CC + 33)         // y needed on [0, C+32]
#define NZ  (CC + 25)         // k1 / z2 range
#define NK2 (CC + 17)         // k2 / z3 range
#define NK3 (CC + 9)          // k3 / z4 range

// ---------------- Cl(3,0) structure constants, compile-time ----------------
// basis [1, e1, e2, e3, e12, e13, e23, e123], masks {0,1,2,4,3,5,6,7}
struct GpTab {
    signed char  s[8][8];   // sign of e_i * e_j
    unsigned char k[8][8];  // result basis index
    signed char  cs[8][8];  // s[i][j] - s[j][i]  (commutator coeff, in {-2,0,2})
    signed char  as[8][8];  // s[i][j] + s[j][i]  (anticommutator coeff, in {-2,0,2})
};

static constexpr GpTab make_tab() {
    GpTab t{};
    const int masks[8] = {0, 1, 2, 4, 3, 5, 6, 7};
    const int idxof[8] = {0, 1, 2, 4, 3, 5, 6, 7};  // mask -> basis index
    for (int i = 0; i < 8; ++i) {
        for (int j = 0; j < 8; ++j) {
            int a = masks[i], b = masks[j];
            int aa = a >> 1, tot = 0;
            while (aa) {
                int x = aa & b;
                while (x) { tot += x & 1; x >>= 1; }
                aa >>= 1;
            }
            t.s[i][j] = (signed char)((tot & 1) ? -1 : 1);
            t.k[i][j] = (unsigned char)idxof[a ^ b];
        }
    }
    for (int i = 0; i < 8; ++i)
        for (int j = 0; j < 8; ++j) {
            t.cs[i][j] = (signed char)(t.s[i][j] - t.s[j][i]);
            t.as[i][j] = (signed char)(t.s[i][j] + t.s[j][i]);
        }
    return t;
}
static constexpr GpTab TAB = make_tab();

// ---------------- multivector primitives (all unrolled, constant-folded) ----
__device__ __forceinline__ void gp8(const float* a, const float* b, float* o) {
    float r[8];
#pragma unroll
    for (int c = 0; c < 8; ++c) r[c] = 0.f;
#pragma unroll
    for (int i = 0; i < 8; ++i) {
#pragma unroll
        for (int j = 0; j < 8; ++j) {
            const int k = TAB.k[i][j];
            if (TAB.s[i][j] > 0) r[k] = fmaf(a[i],  b[j], r[k]);
            else                 r[k] = fmaf(-a[i], b[j], r[k]);
        }
    }
#pragma unroll
    for (int c = 0; c < 8; ++c) o[c] = r[c];
}

// Clifford square: anticommuting cross terms cancel.
__device__ __forceinline__ void sq8(const float* a, float* o) {
    float r[8];
#pragma unroll
    for (int c = 0; c < 8; ++c) r[c] = 0.f;
#pragma unroll
    for (int i = 0; i < 8; ++i) {
        if (TAB.s[i][i] > 0) r[0] = fmaf(a[i],  a[i], r[0]);
        else                 r[0] = fmaf(-a[i], a[i], r[0]);
    }
#pragma unroll
    for (int i = 0; i < 8; ++i) {
#pragma unroll
        for (int j = i + 1; j < 8; ++j) {
            const int as = TAB.as[i][j];
            const int k = TAB.k[i][j];
            if (as > 0)      r[k] = fmaf(a[i],  a[j], r[k]);
            else if (as < 0) r[k] = fmaf(-a[i], a[j], r[k]);
        }
    }
    o[0] = r[0];
#pragma unroll
    for (int c = 1; c < 8; ++c) o[c] = 2.f * r[c];
}

// commutator [a,b] = ab - ba : only anticommuting pairs contribute
__device__ __forceinline__ void comm8(const float* a, const float* b, float* o) {
    float r[8];
#pragma unroll
    for (int c = 0; c < 8; ++c) r[c] = 0.f;
#pragma unroll
    for (int i = 0; i < 8; ++i) {
#pragma unroll
        for (int j = 0; j < 8; ++j) {
            const int cs = TAB.cs[i][j];
            const int k = TAB.k[i][j];
            if (cs > 0)      r[k] = fmaf(a[i],  b[j], r[k]);
            else if (cs < 0) r[k] = fmaf(-a[i], b[j], r[k]);
        }
    }
#pragma unroll
    for (int c = 0; c < 8; ++c) o[c] = 2.f * r[c];
}

// exp(u) truncated at u^7/7! (EXP_TERMS=8), even/odd split
__device__ __forceinline__ void exp8(const float* u, float* o) {
    float u2[8], u4[8], u6[8], E[8], Ob[8], O[8];
    sq8(u, u2);
    sq8(u2, u4);
    gp8(u2, u4, u6);
#pragma unroll
    for (int c = 0; c < 8; ++c) {
        float e = fmaf(1.f / 2.f,  u2[c], (c == 0) ? 1.f : 0.f);
        e = fmaf(1.f / 24.f,  u4[c], e);
        E[c] = fmaf(1.f / 720.f, u6[c], e);
        float ob = fmaf(1.f / 6.f, u2[c], (c == 0) ? 1.f : 0.f);
        ob = fmaf(1.f / 120.f,  u4[c], ob);
        Ob[c] = fmaf(1.f / 5040.f, u6[c], ob);
    }
    gp8(u, Ob, O);
#pragma unroll
    for (int c = 0; c < 8; ++c) o[c] = E[c] + O[c];
}

// dexp^{-1}_u(w), order 4, Bernoulli (1, -1/2, 1/6, 0, -1/30)
__device__ __forceinline__ void dexpinv8(const float* u, const float* w, float* o) {
    float res[8], ad[8], t1[8];
#pragma unroll
    for (int c = 0; c < 8; ++c) { res[c] = w[c]; ad[c] = w[c]; }
    comm8(u, ad, t1);                                   // k=1, c=-1/2
#pragma unroll
    for (int c = 0; c < 8; ++c) { ad[c] = t1[c]; res[c] = fmaf(-0.5f, t1[c], res[c]); }
    comm8(u, ad, t1);                                   // k=2, c=1/12
#pragma unroll
    for (int c = 0; c < 8; ++c) { ad[c] = t1[c]; res[c] = fmaf(1.f / 12.f, t1[c], res[c]); }
    comm8(u, ad, t1);                                   // k=3, c=0
#pragma unroll
    for (int c = 0; c < 8; ++c) ad[c] = t1[c];
    comm8(u, ad, t1);                                   // k=4, c=-1/720
#pragma unroll
    for (int c = 0; c < 8; ++c) o[c] = fmaf(-1.f / 720.f, t1[c], res[c]);
}

// ---------------- LDS access (b128-vectorized, bank-swizzled) ----
// Element e occupies floats [8e, 8e+8); the lo/hi float4 swap when (e&4)
// so that 8 consecutive lanes touch 8 distinct 16B bank-groups.
__device__ __forceinline__ int sbase(int e) { return (e << 3) ^ (e & 4); }

__device__ __forceinline__ void lds_load8(const float* buf, int e, float* o) {
    const int b = sbase(e);
    float4 a = *(const float4*)(buf + b);
    float4 c = *(const float4*)(buf + (b ^ 4));
    o[0] = a.x; o[1] = a.y; o[2] = a.z; o[3] = a.w;
    o[4] = c.x; o[5] = c.y; o[6] = c.z; o[7] = c.w;
}
__device__ __forceinline__ void lds_store8(float* buf, int e, const float* v) {
    const int b = sbase(e);
    *(float4*)(buf + b)       = make_float4(v[0], v[1], v[2], v[3]);
    *(float4*)(buf + (b ^ 4)) = make_float4(v[4], v[5], v[6], v[7]);
}

// vector_field from LDS buffer: derivative + 0.0125 * gp(z, z1 + z2/2 + z4/4 + z8/8)
__device__ __forceinline__ void vf8_lds(const float* buf, int e, float* o) {
    float z0[8], t1[8], t2[8], t4[8], t8[8], bc[8], g[8];
    lds_load8(buf, e,     z0);
    lds_load8(buf, e + 1, t1);
    lds_load8(buf, e + 2, t2);
    lds_load8(buf, e + 4, t4);
    lds_load8(buf, e + 8, t8);
#pragma unroll
    for (int c = 0; c < 8; ++c) {
        float v = fmaf(0.5f, t2[c], t1[c]);
        v = fmaf(0.25f, t4[c], v);
        bc[c] = fmaf(0.125f, t8[c], v);
    }
    gp8(z0, bc, g);
    o[0] = 0.0125f * g[0];
    o[1] = fmaf(0.0125f, g[1],  z0[4]);
    o[2] = fmaf(0.0125f, g[2],  z0[5]);
    o[3] = fmaf(0.0125f, g[3],  z0[6]);
    o[4] = fmaf(0.0125f, g[4], -z0[1]);
    o[5] = fmaf(0.0125f, g[5], -z0[2]);
    o[6] = fmaf(0.0125f, g[6], -z0[3]);
    o[7] = 0.0125f * g[7];
}

// z = gp(exp(scale*k), y[e]) -> zbuf[e]
__device__ __forceinline__ void zstage(const float* ybuf, float* zbuf, int e,
                                       const float* k, float scale) {
    float u[8], ex[8], yv[8], o[8];
#pragma unroll
    for (int c = 0; c < 8; ++c) u[c] = scale * k[c];
    exp8(u, ex);
    lds_load8(ybuf, e, yv);
    gp8(ex, yv, o);
    lds_store8(zbuf, e, o);
}

// kout = dexpinv(scale*kin, vf(z[e]))
__device__ __forceinline__ void kstage(const float* zbuf, int e,
                                       const float* kin, float scale, float* kout) {
    float w[8], u[8];
    vf8_lds(zbuf, e, w);
#pragma unroll
    for (int c = 0; c < 8; ++c) u[c] = scale * kin[c];
    dexpinv8(u, w, kout);
}

__global__ __launch_bounds__(CC, 8)
void clifford_step_kernel(const float* __restrict__ y, float* __restrict__ out) {
    __shared__ __align__(16) float sy[NY * SP];   // 9248 B
    __shared__ __align__(16) float sz[NZ * SP];   // 8992 B  (>= 2048 floats for out-bounce)

    const int tid   = threadIdx.x;
    const int row   = blockIdx.x >> 8;      // 65536/256 = 256 chunks per row
    const int chunk = blockIdx.x & 255;
    const int base  = chunk * CC;
    const float* __restrict__ yrow = y + (size_t)row * 65536u * 8u;

    // ---- load y tile (+halo 32) into LDS ----
    for (int e = tid; e < NY; e += CC) {
        const int gidx = (base + e) & 65535;
        const float4* p = (const float4*)(yrow + (size_t)gidx * 8u);
        float4 a = p[0], b = p[1];
        const int s = sbase(e);
        *(float4*)&sy[s]     = a;
        *(float4*)&sy[s ^ 4] = b;
    }
    __syncthreads();

    // ---- k1 = vf(y)  (registers only; no barrier needed before z2) ----
    float k1a[8], k1b[8];
    vf8_lds(sy, tid, k1a);
    if (tid < NZ - CC) vf8_lds(sy, tid + CC, k1b);

    // ---- z2 = gp(exp(0.05*k1), y) ----
    zstage(sy, sz, tid, k1a, 0.05f);
    if (tid < NZ - CC) zstage(sy, sz, tid + CC, k1b, 0.05f);
    __syncthreads();                         // RAW on sz

    // ---- k2 = dexpinv(0.05*k1, vf(z2)) ----
    float k2a[8], k2b[8];
    kstage(sz, tid, k1a, 0.05f, k2a);
    if (tid < NK2 - CC) kstage(sz, tid + CC, k1b, 0.05f, k2b);
    __syncthreads();                         // WAR: z3 overwrites sz

    // ---- z3 = gp(exp(0.05*k2), y) ----
    zstage(sy, sz, tid, k2a, 0.05f);
    if (tid < NK2 - CC) zstage(sy, sz, tid + CC, k2b, 0.05f);
    __syncthreads();                         // RAW on sz

    // ---- k3 = dexpinv(0.05*k2, vf(z3)) ----
    float k3a[8], k3b[8];
    kstage(sz, tid, k2a, 0.05f, k3a);
    if (tid < NK3 - CC) kstage(sz, tid + CC, k2b, 0.05f, k3b);
    __syncthreads();                         // WAR: z4 overwrites sz

    // ---- z4 = gp(exp(0.1*k3), y) ----
    zstage(sy, sz, tid, k3a, 0.1f);
    if (tid < NK3 - CC) zstage(sy, sz, tid + CC, k3b, 0.1f);
    __syncthreads();                         // RAW on sz

    // ---- tail: k4, u, output (one element per thread) ----
    float o[8];
    {
        const int e = tid;
        float w[8], u4[8], k4[8], u[8], ex[8], yv[8];
        vf8_lds(sz, e, w);
#pragma unroll
        for (int c = 0; c < 8; ++c) u4[c] = 0.1f * k3a[c];
        dexpinv8(u4, w, k4);

        const float s6 = 0.1f / 6.0f;
#pragma unroll
        for (int c = 0; c < 8; ++c) {
            float acc = k1a[c];
            acc = fmaf(2.f, k2a[c], acc);
            acc = fmaf(2.f, k3a[c], acc);
            acc += k4[c];
            float v = s6 * acc;
            if (isnan(v)) v = 0.f;          // nan_to_num(nan=0); clip handles +-inf
            v = fmaxf(-1.f, fminf(v, 1.f)); // clip to [-1, 1]
            u[c] = v;
        }
        exp8(u, ex);
        lds_load8(sy, e, yv);
        gp8(ex, yv, o);
    }

    // ---- bounce result through LDS so global writes are fully contiguous ----
    __syncthreads();                         // all sz/sy reads done
    {
        float4* zf = (float4*)sz;            // 512 float4 = 8192 B <= sizeof(sz)
        const int f0 = 2 * tid, f1 = 2 * tid + 1;
        zf[f0 ^ ((f0 >> 3) & 1)] = make_float4(o[0], o[1], o[2], o[3]);
        zf[f1 ^ ((f1 >> 3) & 1)] = make_float4(o[4], o[5], o[6], o[7]);
    }
    __syncthreads();
    {
        const float4* zf = (const float4*)sz;
        float4* dst = (float4*)(out + ((size_t)row * 65536u + (size_t)base) * 8u);
        const int fa = tid, fb = tid + CC;
        dst[fa] = zf[fa ^ ((fa >> 3) & 1)];
        dst[fb] = zf[fb ^ ((fb >> 3) & 1)];
    }
}

extern "C" void kernel_launch(void* const* d_in, const int* in_sizes, int n_in,
                              void* d_out, int out_size, void* d_ws, size_t ws_size,
                              hipStream_t stream) {
    const float* y = (const float*)d_in[0];
    float* out = (float*)d_out;
    dim3 grid(32 * 256);   // 32 rows x 256 chunks of 256 elements
    dim3 block(CC);
    hipLaunchKernelGGL(clifford_step_kernel, grid, block, 0, stream, y, out);
}

// Round 2
// 171.480 us; speedup vs baseline: 2.7628x; 2.7628x over previous
//
#include <hip/hip_runtime.h>
#include <math.h>

#define CC  256
#define SP  8                 // floats per LDS element slot (32B = 2x float4)
#define NY  (CC + 33)         // y needed on [0, C+32]
#define NZ  (CC + 25)         // k1 / z2 range
#define NK2 (CC + 17)         // k2 / z3 range
#define NK3 (CC + 9)          // k3 / z4 range

// ---------------- Cl(3,0) structure constants, compile-time ----------------
// basis [1, e1, e2, e3, e12, e13, e23, e123], masks {0,1,2,4,3,5,6,7}
struct GpTab {
    signed char  s[8][8];   // sign of e_i * e_j
    unsigned char k[8][8];  // result basis index
    signed char  cs[8][8];  // s[i][j] - s[j][i]  (commutator coeff, in {-2,0,2})
    signed char  as[8][8];  // s[i][j] + s[j][i]  (anticommutator coeff, in {-2,0,2})
};

static constexpr GpTab make_tab() {
    GpTab t{};
    const int masks[8] = {0, 1, 2, 4, 3, 5, 6, 7};
    const int idxof[8] = {0, 1, 2, 4, 3, 5, 6, 7};  // mask -> basis index
    for (int i = 0; i < 8; ++i) {
        for (int j = 0; j < 8; ++j) {
            int a = masks[i], b = masks[j];
            int aa = a >> 1, tot = 0;
            while (aa) {
                int x = aa & b;
                while (x) { tot += x & 1; x >>= 1; }
                aa >>= 1;
            }
            t.s[i][j] = (signed char)((tot & 1) ? -1 : 1);
            t.k[i][j] = (unsigned char)idxof[a ^ b];
        }
    }
    for (int i = 0; i < 8; ++i)
        for (int j = 0; j < 8; ++j) {
            t.cs[i][j] = (signed char)(t.s[i][j] - t.s[j][i]);
            t.as[i][j] = (signed char)(t.s[i][j] + t.s[j][i]);
        }
    return t;
}
static constexpr GpTab TAB = make_tab();

// ---------------- multivector primitives (all unrolled, constant-folded) ----
__device__ __forceinline__ void gp8(const float* a, const float* b, float* o) {
    float r[8];
#pragma unroll
    for (int c = 0; c < 8; ++c) r[c] = 0.f;
#pragma unroll
    for (int i = 0; i < 8; ++i) {
#pragma unroll
        for (int j = 0; j < 8; ++j) {
            const int k = TAB.k[i][j];
            if (TAB.s[i][j] > 0) r[k] = fmaf(a[i],  b[j], r[k]);
            else                 r[k] = fmaf(-a[i], b[j], r[k]);
        }
    }
#pragma unroll
    for (int c = 0; c < 8; ++c) o[c] = r[c];
}

// Clifford square: anticommuting cross terms cancel.
__device__ __forceinline__ void sq8(const float* a, float* o) {
    float r[8];
#pragma unroll
    for (int c = 0; c < 8; ++c) r[c] = 0.f;
#pragma unroll
    for (int i = 0; i < 8; ++i) {
        if (TAB.s[i][i] > 0) r[0] = fmaf(a[i],  a[i], r[0]);
        else                 r[0] = fmaf(-a[i], a[i], r[0]);
    }
#pragma unroll
    for (int i = 0; i < 8; ++i) {
#pragma unroll
        for (int j = i + 1; j < 8; ++j) {
            const int as = TAB.as[i][j];
            const int k = TAB.k[i][j];
            if (as > 0)      r[k] = fmaf(a[i],  a[j], r[k]);
            else if (as < 0) r[k] = fmaf(-a[i], a[j], r[k]);
        }
    }
    o[0] = r[0];
#pragma unroll
    for (int c = 1; c < 8; ++c) o[c] = 2.f * r[c];
}

// commutator [a,b] = ab - ba : only anticommuting pairs contribute
__device__ __forceinline__ void comm8(const float* a, const float* b, float* o) {
    float r[8];
#pragma unroll
    for (int c = 0; c < 8; ++c) r[c] = 0.f;
#pragma unroll
    for (int i = 0; i < 8; ++i) {
#pragma unroll
        for (int j = 0; j < 8; ++j) {
            const int cs = TAB.cs[i][j];
            const int k = TAB.k[i][j];
            if (cs > 0)      r[k] = fmaf(a[i],  b[j], r[k]);
            else if (cs < 0) r[k] = fmaf(-a[i], b[j], r[k]);
        }
    }
#pragma unroll
    for (int c = 0; c < 8; ++c) o[c] = 2.f * r[c];
}

// exp(u) truncated at u^7/7! (EXP_TERMS=8), even/odd split
__device__ __forceinline__ void exp8(const float* u, float* o) {
    float u2[8], u4[8], u6[8], E[8], Ob[8], O[8];
    sq8(u, u2);
    sq8(u2, u4);
    gp8(u2, u4, u6);
#pragma unroll
    for (int c = 0; c < 8; ++c) {
        float e = fmaf(1.f / 2.f,  u2[c], (c == 0) ? 1.f : 0.f);
        e = fmaf(1.f / 24.f,  u4[c], e);
        E[c] = fmaf(1.f / 720.f, u6[c], e);
        float ob = fmaf(1.f / 6.f, u2[c], (c == 0) ? 1.f : 0.f);
        ob = fmaf(1.f / 120.f,  u4[c], ob);
        Ob[c] = fmaf(1.f / 5040.f, u6[c], ob);
    }
    gp8(u, Ob, O);
#pragma unroll
    for (int c = 0; c < 8; ++c) o[c] = E[c] + O[c];
}

// dexp^{-1}_u(w), order 4, Bernoulli (1, -1/2, 1/6, 0, -1/30)
__device__ __forceinline__ void dexpinv8(const float* u, const float* w, float* o) {
    float res[8], ad[8], t1[8];
#pragma unroll
    for (int c = 0; c < 8; ++c) { res[c] = w[c]; ad[c] = w[c]; }
    comm8(u, ad, t1);                                   // k=1, c=-1/2
#pragma unroll
    for (int c = 0; c < 8; ++c) { ad[c] = t1[c]; res[c] = fmaf(-0.5f, t1[c], res[c]); }
    comm8(u, ad, t1);                                   // k=2, c=1/12
#pragma unroll
    for (int c = 0; c < 8; ++c) { ad[c] = t1[c]; res[c] = fmaf(1.f / 12.f, t1[c], res[c]); }
    comm8(u, ad, t1);                                   // k=3, c=0
#pragma unroll
    for (int c = 0; c < 8; ++c) ad[c] = t1[c];
    comm8(u, ad, t1);                                   // k=4, c=-1/720
#pragma unroll
    for (int c = 0; c < 8; ++c) o[c] = fmaf(-1.f / 720.f, t1[c], res[c]);
}

// ---------------- LDS access (b128-vectorized, bank-swizzled) ----
// Element e occupies floats [8e, 8e+8); the lo/hi float4 swap when (e&4)
// so that 8 consecutive lanes touch 8 distinct 16B bank-groups.
__device__ __forceinline__ int sbase(int e) { return (e << 3) ^ (e & 4); }

__device__ __forceinline__ void lds_load8(const float* buf, int e, float* o) {
    const int b = sbase(e);
    float4 a = *(const float4*)(buf + b);
    float4 c = *(const float4*)(buf + (b ^ 4));
    o[0] = a.x; o[1] = a.y; o[2] = a.z; o[3] = a.w;
    o[4] = c.x; o[5] = c.y; o[6] = c.z; o[7] = c.w;
}
__device__ __forceinline__ void lds_store8(float* buf, int e, const float* v) {
    const int b = sbase(e);
    *(float4*)(buf + b)       = make_float4(v[0], v[1], v[2], v[3]);
    *(float4*)(buf + (b ^ 4)) = make_float4(v[4], v[5], v[6], v[7]);
}

// vector_field from LDS buffer: derivative + 0.0125 * gp(z, z1 + z2/2 + z4/4 + z8/8)
__device__ __forceinline__ void vf8_lds(const float* buf, int e, float* o) {
    float z0[8], t1[8], t2[8], t4[8], t8[8], bc[8], g[8];
    lds_load8(buf, e,     z0);
    lds_load8(buf, e + 1, t1);
    lds_load8(buf, e + 2, t2);
    lds_load8(buf, e + 4, t4);
    lds_load8(buf, e + 8, t8);
#pragma unroll
    for (int c = 0; c < 8; ++c) {
        float v = fmaf(0.5f, t2[c], t1[c]);
        v = fmaf(0.25f, t4[c], v);
        bc[c] = fmaf(0.125f, t8[c], v);
    }
    gp8(z0, bc, g);
    o[0] = 0.0125f * g[0];
    o[1] = fmaf(0.0125f, g[1],  z0[4]);
    o[2] = fmaf(0.0125f, g[2],  z0[5]);
    o[3] = fmaf(0.0125f, g[3],  z0[6]);
    o[4] = fmaf(0.0125f, g[4], -z0[1]);
    o[5] = fmaf(0.0125f, g[5], -z0[2]);
    o[6] = fmaf(0.0125f, g[6], -z0[3]);
    o[7] = 0.0125f * g[7];
}

// z = gp(exp(scale*k), y[e]) -> zbuf[e]
__device__ __forceinline__ void zstage(const float* ybuf, float* zbuf, int e,
                                       const float* k, float scale) {
    float u[8], ex[8], yv[8], o[8];
#pragma unroll
    for (int c = 0; c < 8; ++c) u[c] = scale * k[c];
    exp8(u, ex);
    lds_load8(ybuf, e, yv);
    gp8(ex, yv, o);
    lds_store8(zbuf, e, o);
}

// kout = dexpinv(scale*kin, vf(z[e]))
__device__ __forceinline__ void kstage(const float* zbuf, int e,
                                       const float* kin, float scale, float* kout) {
    float w[8], u[8];
    vf8_lds(zbuf, e, w);
#pragma unroll
    for (int c = 0; c < 8; ++c) u[c] = scale * kin[c];
    dexpinv8(u, w, kout);
}

__global__ __launch_bounds__(CC, 4)
void clifford_step_kernel(const float* __restrict__ y, float* __restrict__ out) {
    __shared__ __align__(16) float sy[NY * SP];   // 9248 B
    __shared__ __align__(16) float sz[NZ * SP];   // 8992 B  (>= 2048 floats for out-bounce)

    const int tid   = threadIdx.x;
    const int row   = blockIdx.x >> 8;      // 65536/256 = 256 chunks per row
    const int chunk = blockIdx.x & 255;
    const int base  = chunk * CC;
    const float* __restrict__ yrow = y + (size_t)row * 65536u * 8u;

    // ---- load y tile (+halo 32) into LDS ----
    for (int e = tid; e < NY; e += CC) {
        const int gidx = (base + e) & 65535;
        const float4* p = (const float4*)(yrow + (size_t)gidx * 8u);
        float4 a = p[0], b = p[1];
        const int s = sbase(e);
        *(float4*)&sy[s]     = a;
        *(float4*)&sy[s ^ 4] = b;
    }
    __syncthreads();

    // ---- k1 = vf(y)  (registers only; no barrier needed before z2) ----
    float k1a[8], k1b[8];
    vf8_lds(sy, tid, k1a);
    if (tid < NZ - CC) vf8_lds(sy, tid + CC, k1b);

    // ---- z2 = gp(exp(0.05*k1), y) ----
    zstage(sy, sz, tid, k1a, 0.05f);
    if (tid < NZ - CC) zstage(sy, sz, tid + CC, k1b, 0.05f);
    __syncthreads();                         // RAW on sz

    // ---- k2 = dexpinv(0.05*k1, vf(z2)) ----
    float k2a[8], k2b[8];
    kstage(sz, tid, k1a, 0.05f, k2a);
    if (tid < NK2 - CC) kstage(sz, tid + CC, k1b, 0.05f, k2b);
    __syncthreads();                         // WAR: z3 overwrites sz

    // ---- z3 = gp(exp(0.05*k2), y) ----
    zstage(sy, sz, tid, k2a, 0.05f);
    if (tid < NK2 - CC) zstage(sy, sz, tid + CC, k2b, 0.05f);
    __syncthreads();                         // RAW on sz

    // ---- k3 = dexpinv(0.05*k2, vf(z3)) ----
    float k3a[8], k3b[8];
    kstage(sz, tid, k2a, 0.05f, k3a);
    if (tid < NK3 - CC) kstage(sz, tid + CC, k2b, 0.05f, k3b);
    __syncthreads();                         // WAR: z4 overwrites sz

    // ---- z4 = gp(exp(0.1*k3), y) ----
    zstage(sy, sz, tid, k3a, 0.1f);
    if (tid < NK3 - CC) zstage(sy, sz, tid + CC, k3b, 0.1f);
    __syncthreads();                         // RAW on sz

    // ---- tail: k4, u, output (one element per thread) ----
    float o[8];
    {
        const int e = tid;
        float w[8], u4[8], k4[8], u[8], ex[8], yv[8];
        vf8_lds(sz, e, w);
#pragma unroll
        for (int c = 0; c < 8; ++c) u4[c] = 0.1f * k3a[c];
        dexpinv8(u4, w, k4);

        const float s6 = 0.1f / 6.0f;
#pragma unroll
        for (int c = 0; c < 8; ++c) {
            float acc = k1a[c];
            acc = fmaf(2.f, k2a[c], acc);
            acc = fmaf(2.f, k3a[c], acc);
            acc += k4[c];
            float v = s6 * acc;
            if (isnan(v)) v = 0.f;          // nan_to_num(nan=0); clip handles +-inf
            v = fmaxf(-1.f, fminf(v, 1.f)); // clip to [-1, 1]
            u[c] = v;
        }
        exp8(u, ex);
        lds_load8(sy, e, yv);
        gp8(ex, yv, o);
    }

    // ---- bounce result through LDS so global writes are fully contiguous ----
    __syncthreads();                         // all sz/sy reads done
    {
        float4* zf = (float4*)sz;            // 512 float4 = 8192 B <= sizeof(sz)
        const int f0 = 2 * tid, f1 = 2 * tid + 1;
        zf[f0 ^ ((f0 >> 3) & 1)] = make_float4(o[0], o[1], o[2], o[3]);
        zf[f1 ^ ((f1 >> 3) & 1)] = make_float4(o[4], o[5], o[6], o[7]);
    }
    __syncthreads();
    {
        const float4* zf = (const float4*)sz;
        float4* dst = (float4*)(out + ((size_t)row * 65536u + (size_t)base) * 8u);
        const int fa = tid, fb = tid + CC;
        dst[fa] = zf[fa ^ ((fa >> 3) & 1)];
        dst[fb] = zf[fb ^ ((fb >> 3) & 1)];
    }
}

extern "C" void kernel_launch(void* const* d_in, const int* in_sizes, int n_in,
                              void* d_out, int out_size, void* d_ws, size_t ws_size,
                              hipStream_t stream) {
    const float* y = (const float*)d_in[0];
    float* out = (float*)d_out;
    dim3 grid(32 * 256);   // 32 rows x 256 chunks of 256 elements
    dim3 block(CC);
    hipLaunchKernelGGL(clifford_step_kernel, grid, block, 0, stream, y, out);
}

// Round 4
// 92.817 us; speedup vs baseline: 5.1042x; 1.8475x over previous
//
#include <hip/hip_runtime.h>
#include <math.h>

#define CC   256
#define SP   8                 // floats per LDS element slot (32B = 2x float4)
#define NY   (CC + 33)         // y needed on [0, C+32]
#define NZ   (CC + 25)         // k1 / z2 range
#define NK2  (CC + 17)         // k2 / z3 range
#define NK3  (CC + 9)          // k3 / z4 range
#define ISCL 0.0125f           // INTERACTION_SCALE / len(SHIFTS)

// ============================================================================
// Cl(3,0) ~= M2(C) via Pauli matrices:  e1->s1, e2->s2, e3->s3,
// e12 = i s3, e13 = -i s2, e23 = i s1, e123 = i I.
// Multivector a[8] (basis [1,e1,e2,e3,e12,e13,e23,e123]) <-> matrix
//   M = [[ (a0+a3)+i(a7+a4) , (a1-a5)+i(a6-a2) ],
//        [ (a1+a5)+i(a6+a2) , (a0-a3)+i(a7-a4) ]]
// stored as float m[8] = {M00r,M00i, M01r,M01i, M10r,M10i, M11r,M11i}.
// Geometric product == matrix product (exact isomorphism).
// ============================================================================

// ---------------- complex primitives ----------------
__device__ __forceinline__ void cmul(float& orr, float& oi,
                                     float ar, float ai, float br, float bi) {
    orr = fmaf(ar, br, -(ai * bi));
    oi  = fmaf(ar, bi,   ai * br);
}
__device__ __forceinline__ void cmad(float& orr, float& oi,
                                     float ar, float ai, float br, float bi) {
    orr = fmaf(ar, br, fmaf(-ai, bi, orr));
    oi  = fmaf(ar, bi, fmaf( ai, br, oi));
}
__device__ __forceinline__ void cmsub(float& orr, float& oi,
                                      float ar, float ai, float br, float bi) {
    orr = fmaf(-ar, br, fmaf( ai, bi, orr));
    oi  = fmaf(-ar, bi, fmaf(-ai, br, oi));
}

// o = a * b  (2x2 complex matmul, 32 FMA)
__device__ __forceinline__ void mm2(const float* a, const float* b, float* o) {
    float r0,r1,r2,r3,r4,r5,r6,r7;
    cmul(r0,r1, a[0],a[1], b[0],b[1]); cmad(r0,r1, a[2],a[3], b[4],b[5]);
    cmul(r2,r3, a[0],a[1], b[2],b[3]); cmad(r2,r3, a[2],a[3], b[6],b[7]);
    cmul(r4,r5, a[4],a[5], b[0],b[1]); cmad(r4,r5, a[6],a[7], b[4],b[5]);
    cmul(r6,r7, a[4],a[5], b[2],b[3]); cmad(r6,r7, a[6],a[7], b[6],b[7]);
    o[0]=r0; o[1]=r1; o[2]=r2; o[3]=r3; o[4]=r4; o[5]=r5; o[6]=r6; o[7]=r7;
}

// ---------------- commutator (traceless operands) ----------------
// [A,W] with A traceless (u6 = {A00, A01, A10}); W given by off-diagonals
// W01, W10 and diagonal difference dW = W00 - W11. Result traceless:
//   C00 = A01*W10 - A10*W01 ; C01 = W01*dA - A01*dW ; C10 = A10*dW - W10*dA
// where dA = 2*A00.
__device__ __forceinline__ void comm_core2(const float* u6,
        float w01r, float w01i, float w10r, float w10i,
        float dwr, float dwi, float* o6) {
    const float dar = 2.f * u6[0], dai = 2.f * u6[1];
    float ar, ai;
    cmul (ar, ai, u6[2],u6[3], w10r,w10i);     // A01*W10
    cmsub(ar, ai, u6[4],u6[5], w01r,w01i);     // - A10*W01
    o6[0] = ar; o6[1] = ai;
    cmul (ar, ai, w01r,w01i, dar,dai);         // W01*dA
    cmsub(ar, ai, u6[2],u6[3], dwr,dwi);       // - A01*dW
    o6[2] = ar; o6[3] = ai;
    cmul (ar, ai, u6[4],u6[5], dwr,dwi);       // A10*dW
    cmsub(ar, ai, w10r,w10i, dar,dai);         // - W10*dA
    o6[4] = ar; o6[5] = ai;
}

// dexp^{-1}_{s*k}(w), order 4, Bernoulli (1,-1/2,1/6,0,-1/30).
// Central part of k commutes with everything -> use traceless part only;
// scale s folded into coefficients (ad_{sk}^n = s^n ad_k^n).
__device__ __forceinline__ void dexpinv8(const float* k, const float* w,
                                         float s, float* o) {
    float u6[6];
    u6[0] = 0.5f*(k[0]-k[6]); u6[1] = 0.5f*(k[1]-k[7]);
    u6[2] = k[2]; u6[3] = k[3]; u6[4] = k[4]; u6[5] = k[5];
    float a1[6], a2[6], a3[6], a4[6];
    comm_core2(u6, w[2],w[3], w[4],w[5], w[0]-w[6], w[1]-w[7], a1);
    comm_core2(u6, a1[2],a1[3], a1[4],a1[5], 2.f*a1[0], 2.f*a1[1], a2);
    comm_core2(u6, a2[2],a2[3], a2[4],a2[5], 2.f*a2[0], 2.f*a2[1], a3);
    comm_core2(u6, a3[2],a3[3], a3[4],a3[5], 2.f*a3[0], 2.f*a3[1], a4);
    const float s2 = s*s;
    const float c1 = -0.5f*s, c2 = s2*(1.f/12.f), c4 = -(s2*s2)*(1.f/720.f);
    const float t0 = fmaf(c1,a1[0], fmaf(c2,a2[0], c4*a4[0]));
    const float t1 = fmaf(c1,a1[1], fmaf(c2,a2[1], c4*a4[1]));
    const float t2 = fmaf(c1,a1[2], fmaf(c2,a2[2], c4*a4[2]));
    const float t3 = fmaf(c1,a1[3], fmaf(c2,a2[3], c4*a4[3]));
    const float t4 = fmaf(c1,a1[4], fmaf(c2,a2[4], c4*a4[4]));
    const float t5 = fmaf(c1,a1[5], fmaf(c2,a2[5], c4*a4[5]));
    o[0] = w[0] + t0; o[1] = w[1] + t1;
    o[2] = w[2] + t2; o[3] = w[3] + t3;
    o[4] = w[4] + t4; o[5] = w[5] + t5;
    o[6] = w[6] - t0; o[7] = w[7] - t1;
}

// ---------------- closed-form exp ----------------
// exp(s*k) = e^{c0} (cosh(d) I + sinhc(d) V), c0 = central part, V traceless,
// d^2 = w = V00^2 + V01*V10. cosh/sinhc computed as entire series in w
// (5 terms; |w| <= 4 even at clip bounds -> err <= 3e-4, typical ~1e-9).
__device__ __forceinline__ void chstep(float& pr, float& pi,
                                       float wr, float wi, float K) {
    const float nr = fmaf(pr, wr, fmaf(-pi, wi, K));
    const float ni = fmaf(pr, wi, pi * wr);
    pr = nr; pi = ni;
}
__device__ __forceinline__ void expm(const float* k, float s, float* o) {
    const float hs = 0.5f * s;
    const float c0r = hs*(k[0]+k[6]), c0i = hs*(k[1]+k[7]);
    const float v0r = hs*(k[0]-k[6]), v0i = hs*(k[1]-k[7]);
    const float v1r = s*k[2], v1i = s*k[3];
    const float v2r = s*k[4], v2i = s*k[5];
    float wr = fmaf(v0r, v0r, -(v0i*v0i));
    wr = fmaf(v1r, v2r, wr); wr = fmaf(-v1i, v2i, wr);
    float wi = 2.f*v0r*v0i;
    wi = fmaf(v1r, v2i, wi); wi = fmaf(v1i, v2r, wi);
    float Cr = 1.f/40320.f, Ci = 0.f;          // cosh: 1,1/2,1/24,1/720,1/40320
    chstep(Cr, Ci, wr, wi, 1.f/720.f);
    chstep(Cr, Ci, wr, wi, 1.f/24.f);
    chstep(Cr, Ci, wr, wi, 0.5f);
    chstep(Cr, Ci, wr, wi, 1.f);
    float Sr = 1.f/362880.f, Si = 0.f;         // sinhc: 1,1/6,1/120,1/5040,1/362880
    chstep(Sr, Si, wr, wi, 1.f/5040.f);
    chstep(Sr, Si, wr, wi, 1.f/120.f);
    chstep(Sr, Si, wr, wi, 1.f/6.f);
    chstep(Sr, Si, wr, wi, 1.f);
    const float ex = __expf(c0r);
    const float cs = __cosf(c0i), sn = __sinf(c0i);
    const float er = ex*cs, ei = ex*sn;        // e^{c0}
    float p0r, p0i; cmul(p0r, p0i, Sr, Si, v0r, v0i);     // S*V00
    const float tr = Cr + p0r, ti = Ci + p0i;
    const float ur = Cr - p0r, ui = Ci - p0i;
    cmul(o[0], o[1], er, ei, tr, ti);
    cmul(o[6], o[7], er, ei, ur, ui);
    float qr, qi; cmul(qr, qi, er, ei, Sr, Si);           // e^{c0}*S
    cmul(o[2], o[3], qr, qi, v1r, v1i);
    cmul(o[4], o[5], qr, qi, v2r, v2i);
}

// ---------------- LDS access (b128-vectorized, bank-swizzled) ----------------
__device__ __forceinline__ int sbase(int e) { return (e << 3) ^ (e & 4); }

__device__ __forceinline__ void lds_load8(const float* buf, int e, float* o) {
    const int b = sbase(e);
    float4 a = *(const float4*)(buf + b);
    float4 c = *(const float4*)(buf + (b ^ 4));
    o[0] = a.x; o[1] = a.y; o[2] = a.z; o[3] = a.w;
    o[4] = c.x; o[5] = c.y; o[6] = c.z; o[7] = c.w;
}
__device__ __forceinline__ void lds_store8(float* buf, int e, const float* v) {
    const int b = sbase(e);
    *(float4*)(buf + b)       = make_float4(v[0], v[1], v[2], v[3]);
    *(float4*)(buf + (b ^ 4)) = make_float4(v[4], v[5], v[6], v[7]);
}

// vector_field (matrix rep): derivative map + ISCL * z0 * bc
// derivative in sigma-coeffs: (c1,c2,c3) -> (-i c3, i c2, -i c1), central -> 0.
__device__ __forceinline__ void vf8_lds(const float* buf, int e, float* o) {
    float z0[8], t1[8], t2[8], t4[8], t8[8], bc[8], g[8];
    lds_load8(buf, e,     z0);
    lds_load8(buf, e + 1, t1);
    lds_load8(buf, e + 2, t2);
    lds_load8(buf, e + 4, t4);
    lds_load8(buf, e + 8, t8);
#pragma unroll
    for (int c = 0; c < 8; ++c)
        bc[c] = fmaf(0.125f, t8[c], fmaf(0.25f, t4[c], fmaf(0.5f, t2[c], t1[c])));
    mm2(z0, bc, g);
    const float Sr  = z0[2]+z0[4], Si  = z0[3]+z0[5];   // M01+M10
    const float Ddr = z0[0]-z0[6], Ddi = z0[1]-z0[7];   // M00-M11
    const float Tr  = z0[4]-z0[2], Ti  = z0[5]-z0[3];   // M10-M01
    o[0] = fmaf(ISCL, g[0],  0.5f*Si);
    o[1] = fmaf(ISCL, g[1], -0.5f*Sr);
    o[2] = fmaf(ISCL, g[2],  0.5f*(Ddi+Ti));
    o[3] = fmaf(ISCL, g[3], -0.5f*(Ddr+Tr));
    o[4] = fmaf(ISCL, g[4],  0.5f*(Ddi-Ti));
    o[5] = fmaf(ISCL, g[5], -0.5f*(Ddr-Tr));
    o[6] = fmaf(ISCL, g[6], -0.5f*Si);
    o[7] = fmaf(ISCL, g[7],  0.5f*Sr);
}

// z = exp(scale*k) * y[e] -> zbuf[e]
__device__ __forceinline__ void zstage(const float* ybuf, float* zbuf, int e,
                                       const float* k, float scale) {
    float ex[8], yv[8], o[8];
    expm(k, scale, ex);
    lds_load8(ybuf, e, yv);
    mm2(ex, yv, o);
    lds_store8(zbuf, e, o);
}

// kout = dexpinv(scale*kin, vf(z[e]))
__device__ __forceinline__ void kstage(const float* zbuf, int e,
                                       const float* kin, float scale, float* kout) {
    float w[8];
    vf8_lds(zbuf, e, w);
    dexpinv8(kin, w, scale, kout);
}

__global__ __launch_bounds__(CC, 4)
void clifford_step_kernel(const float* __restrict__ y, float* __restrict__ out) {
    __shared__ __align__(16) float sy[NY * SP];   // 9248 B (matrix rep)
    __shared__ __align__(16) float sz[NZ * SP];   // 8992 B

    const int tid   = threadIdx.x;
    const int row   = blockIdx.x >> 8;      // 65536/256 = 256 chunks per row
    const int chunk = blockIdx.x & 255;
    const int base  = chunk * CC;
    // rotate the halo-heavy wave per block so heavy waves spread across SIMDs
    const int bt    = (tid - ((blockIdx.x & 3) << 6)) & 255;
    const float* __restrict__ yrow = y + (size_t)row * 65536u * 8u;

    // ---- load y tile (+halo 32) into LDS, converting mv -> matrix ----
    {
        const int g0 = (base + tid) & 65535;
        const float4* p = (const float4*)(yrow + (size_t)g0 * 8u);
        float4 A = p[0], B = p[1];     // a0..a3 | a4..a7
        const int s = sbase(tid);
        *(float4*)&sy[s]     = make_float4(A.x + A.w, B.w + B.x, A.y - B.y, B.z - A.z);
        *(float4*)&sy[s ^ 4] = make_float4(A.y + B.y, B.z + A.z, A.x - A.w, B.w - B.x);
        if (bt < NY - CC) {
            const int e  = CC + bt;
            const int g1 = (base + e) & 65535;
            const float4* q = (const float4*)(yrow + (size_t)g1 * 8u);
            float4 Cv = q[0], D = q[1];
            const int s2 = sbase(e);
            *(float4*)&sy[s2]     = make_float4(Cv.x + Cv.w, D.w + D.x, Cv.y - D.y, D.z - Cv.z);
            *(float4*)&sy[s2 ^ 4] = make_float4(Cv.y + D.y, D.z + Cv.z, Cv.x - Cv.w, D.w - D.x);
        }
    }
    __syncthreads();

    // ---- k1 = vf(y) ----
    float k1a[8], k1b[8];
    vf8_lds(sy, tid, k1a);
    if (bt < NZ - CC) vf8_lds(sy, CC + bt, k1b);

    // ---- z2 = exp(0.05*k1) * y ----
    zstage(sy, sz, tid, k1a, 0.05f);
    if (bt < NZ - CC) zstage(sy, sz, CC + bt, k1b, 0.05f);
    __syncthreads();                         // RAW on sz

    // ---- k2 = dexpinv(0.05*k1, vf(z2)) ----
    float k2a[8], k2b[8];
    kstage(sz, tid, k1a, 0.05f, k2a);
    if (bt < NK2 - CC) kstage(sz, CC + bt, k1b, 0.05f, k2b);
    __syncthreads();                         // WAR: z3 overwrites sz

    // ---- z3 = exp(0.05*k2) * y ----
    zstage(sy, sz, tid, k2a, 0.05f);
    if (bt < NK2 - CC) zstage(sy, sz, CC + bt, k2b, 0.05f);
    __syncthreads();                         // RAW on sz

    // ---- k3 = dexpinv(0.05*k2, vf(z3)) ----
    float k3a[8], k3b[8];
    kstage(sz, tid, k2a, 0.05f, k3a);
    if (bt < NK3 - CC) kstage(sz, CC + bt, k2b, 0.05f, k3b);
    __syncthreads();                         // WAR: z4 overwrites sz

    // ---- z4 = exp(0.1*k3) * y ----
    zstage(sy, sz, tid, k3a, 0.1f);
    if (bt < NK3 - CC) zstage(sy, sz, CC + bt, k3b, 0.1f);
    __syncthreads();                         // RAW on sz

    // ---- tail: k4, u (sanitized in mv basis), output ----
    {
        const int e = tid;
        float w[8], k4[8], um[8], ex[8], yv[8], om[8];
        vf8_lds(sz, e, w);
        dexpinv8(k3a, w, 0.1f, k4);

        const float s6 = 0.1f / 6.0f;
#pragma unroll
        for (int c = 0; c < 8; ++c) {
            float acc = fmaf(2.f, k2a[c], k1a[c]);
            acc = fmaf(2.f, k3a[c], acc);
            acc += k4[c];
            um[c] = s6 * acc;
        }
        // matrix -> multivector coeffs, nan_to_num + clip, -> matrix
        float av[8];
        av[0] = 0.5f*(um[0]+um[6]); av[3] = 0.5f*(um[0]-um[6]);
        av[7] = 0.5f*(um[1]+um[7]); av[4] = 0.5f*(um[1]-um[7]);
        av[1] = 0.5f*(um[2]+um[4]); av[5] = 0.5f*(um[4]-um[2]);
        av[6] = 0.5f*(um[3]+um[5]); av[2] = 0.5f*(um[5]-um[3]);
#pragma unroll
        for (int c = 0; c < 8; ++c) {
            float v = av[c];
            if (isnan(v)) v = 0.f;           // nan_to_num(nan=0); clip handles +-inf
            av[c] = fmaxf(-1.f, fminf(v, 1.f));
        }
        um[0] = av[0]+av[3]; um[1] = av[7]+av[4];
        um[2] = av[1]-av[5]; um[3] = av[6]-av[2];
        um[4] = av[1]+av[5]; um[5] = av[6]+av[2];
        um[6] = av[0]-av[3]; um[7] = av[7]-av[4];

        expm(um, 1.f, ex);
        lds_load8(sy, e, yv);
        mm2(ex, yv, om);

        float* dst = out + ((size_t)row * 65536u + (size_t)(base + e)) * 8u;
        ((float4*)dst)[0] = make_float4(0.5f*(om[0]+om[6]), 0.5f*(om[2]+om[4]),
                                        0.5f*(om[5]-om[3]), 0.5f*(om[0]-om[6]));
        ((float4*)dst)[1] = make_float4(0.5f*(om[1]-om[7]), 0.5f*(om[4]-om[2]),
                                        0.5f*(om[3]+om[5]), 0.5f*(om[1]+om[7]));
    }
}

extern "C" void kernel_launch(void* const* d_in, const int* in_sizes, int n_in,
                              void* d_out, int out_size, void* d_ws, size_t ws_size,
                              hipStream_t stream) {
    const float* y = (const float*)d_in[0];
    float* out = (float*)d_out;
    dim3 grid(32 * 256);   // 32 rows x 256 chunks of 256 elements
    dim3 block(CC);
    hipLaunchKernelGGL(clifford_step_kernel, grid, block, 0, stream, y, out);
}